// Round 2
// baseline (553.045 us; speedup 1.0000x reference)
//
#include <hip/hip_runtime.h>

#define BATCH 16
#define SEQ   2048
#define DIM   64
#define TQ    64
#define TK    64
#define PAD   65          // LDS row stride (floats): bank = (row + d) % 32, conflict-free scalar reads
#define NTHREADS 256

// ---- exact JAX *partitionable* threefry2x32, key = PRNGKey(42) -> (0, 42) ----
// For 32-bit random_bits with jax_threefry_partitionable=True (default since
// JAX 0.4.30): per element flat index f, counter = (hi32(f), lo32(f)) and the
// output word is out0 ^ out1.  Here total size 2^26 < 2^32 so hi == 0.
__device__ __forceinline__ unsigned rotl_(unsigned x, unsigned n) {
  return (x << n) | (x >> (32u - n));
}

__device__ __forceinline__ float tf_uniform(unsigned f) {
  unsigned x0 = 0u;        // counts_hi = 0
  unsigned x1 = f;         // counts_lo = f
  const unsigned ks0 = 0u;
  const unsigned ks1 = 42u;
  const unsigned ks2 = 0x1BD11BDAu ^ 42u;
  x0 += ks0; x1 += ks1;
#define TF_ROUND(r) { x0 += x1; x1 = rotl_(x1, r); x1 ^= x0; }
  TF_ROUND(13u) TF_ROUND(15u) TF_ROUND(26u) TF_ROUND(6u)
  x0 += ks1; x1 += ks2 + 1u;
  TF_ROUND(17u) TF_ROUND(29u) TF_ROUND(16u) TF_ROUND(24u)
  x0 += ks2; x1 += ks0 + 2u;
  TF_ROUND(13u) TF_ROUND(15u) TF_ROUND(26u) TF_ROUND(6u)
  x0 += ks0; x1 += ks1 + 3u;
  TF_ROUND(17u) TF_ROUND(29u) TF_ROUND(16u) TF_ROUND(24u)
  x0 += ks1; x1 += ks2 + 4u;
  TF_ROUND(13u) TF_ROUND(15u) TF_ROUND(26u) TF_ROUND(6u)
  x0 += ks2; x1 += ks0 + 5u;
#undef TF_ROUND
  const unsigned bits = x0 ^ x1;   // partitionable 32-bit path: xor of the pair
  return __uint_as_float((bits >> 9) | 0x3F800000u) - 1.0f;   // [0,1)
}

__global__ __launch_bounds__(NTHREADS, 2)
void attn_fwd(const float* __restrict__ q, const float* __restrict__ k,
              const float* __restrict__ v, const int* __restrict__ mask,
              float* __restrict__ out) {
  __shared__ float QS[TQ * PAD];
  __shared__ float KVS[TK * PAD];   // K during QK^T, then V during PV
  __shared__ float SS[TQ * PAD];    // scores -> dropped probabilities
  __shared__ float m_row[TQ], l_row[TQ], a_row[TQ];
  __shared__ float pmax[TQ * 4], psum[TQ * 4];

  const int t  = threadIdx.x;
  const int bb = blockIdx.x >> 5;          // batch 0..15
  const int q0 = (blockIdx.x & 31) * TQ;   // q-tile origin
  const float ds = (float)(1.0 / 0.9);     // inverted-dropout scale

  const int ty = t >> 4;                   // 0..15
  const int tx = t & 15;                   // 0..15
  const int r0 = 4 * ty;                   // micro-tile rows
  const int c0 = 4 * tx;                   // micro-tile cols

  // ---- stage Q (pre-scaled by 1/sqrt(64)) ----
  {
    const float* qb = q + ((size_t)bb * SEQ + q0) * DIM;
    const int row0 = t >> 4;               // 0..15
    const int dd = (t & 15) * 4;           // 0..60 (coalesced: 16 lanes span a row)
#pragma unroll
    for (int p = 0; p < 4; ++p) {
      const int rr = p * 16 + row0;
      const float4 val = *(const float4*)(qb + rr * DIM + dd);
      float* dst = &QS[rr * PAD + dd];
      dst[0] = val.x * 0.125f; dst[1] = val.y * 0.125f;
      dst[2] = val.z * 0.125f; dst[3] = val.w * 0.125f;
    }
  }
  if (t < TQ) { m_row[t] = -1e30f; l_row[t] = 0.0f; }
  float acc[4][4];
#pragma unroll
  for (int i = 0; i < 4; ++i)
#pragma unroll
    for (int j = 0; j < 4; ++j) acc[i][j] = 0.0f;
  __syncthreads();

#pragma unroll 1
  for (int kt = 0; kt < SEQ / TK; ++kt) {
    const int k0 = kt * TK;
    // ---- stage K ----
    {
      const float* kb = k + ((size_t)bb * SEQ + k0) * DIM;
      const int row0 = t >> 4;
      const int dd = (t & 15) * 4;
#pragma unroll
      for (int p = 0; p < 4; ++p) {
        const int rr = p * 16 + row0;
        const float4 val = *(const float4*)(kb + rr * DIM + dd);
        float* dst = &KVS[rr * PAD + dd];
        dst[0] = val.x; dst[1] = val.y; dst[2] = val.z; dst[3] = val.w;
      }
    }
    __syncthreads();

    // ---- S = Qs K^T (4x4 micro-tile per thread) ----
    float sc[4][4];
#pragma unroll
    for (int i = 0; i < 4; ++i)
#pragma unroll
      for (int j = 0; j < 4; ++j) sc[i][j] = 0.0f;
#pragma unroll 8
    for (int d = 0; d < DIM; ++d) {
      float qv[4], kv[4];
#pragma unroll
      for (int i = 0; i < 4; ++i) qv[i] = QS[(r0 + i) * PAD + d];
#pragma unroll
      for (int j = 0; j < 4; ++j) kv[j] = KVS[(c0 + j) * PAD + d];
#pragma unroll
      for (int i = 0; i < 4; ++i)
#pragma unroll
        for (int j = 0; j < 4; ++j)
          sc[i][j] = fmaf(qv[i], kv[j], sc[i][j]);
    }
    // ---- apply mask, write scores to LDS ----
#pragma unroll
    for (int i = 0; i < 4; ++i) {
      const int4 mv = *(const int4*)(mask + (size_t)(q0 + r0 + i) * SEQ + (k0 + c0));
      float* srow = &SS[(r0 + i) * PAD + c0];
      srow[0] = mv.x ? sc[i][0] : -1e30f;
      srow[1] = mv.y ? sc[i][1] : -1e30f;
      srow[2] = mv.z ? sc[i][2] : -1e30f;
      srow[3] = mv.w ? sc[i][3] : -1e30f;
    }
    __syncthreads();

    // ---- row-tile max (4 partials per row) ----
    {
      const int r = t >> 2, part = t & 3;
      const float* srow = &SS[r * PAD + part * 16];
      float mx = srow[0];
#pragma unroll
      for (int j = 1; j < 16; ++j) mx = fmaxf(mx, srow[j]);
      pmax[r * 4 + part] = mx;
    }
    __syncthreads();
    if (t < TQ) {
      const float mt = fmaxf(fmaxf(pmax[t * 4], pmax[t * 4 + 1]),
                             fmaxf(pmax[t * 4 + 2], pmax[t * 4 + 3]));
      const float mo = m_row[t];
      const float mn = fmaxf(mo, mt);
      m_row[t] = mn;
      a_row[t] = __expf(mo - mn);   // exp(-huge)->0, exp(0)=1 when nothing seen yet
    }
    __syncthreads();

    // ---- exp, dropout (exact JAX partitionable threefry), partial row sums ----
    {
      const int r = t >> 2, part = t & 3;
      const float mn = m_row[r];
      float* srow = &SS[r * PAD + part * 16];
      // global flat index into keep[B, Sq, Sk]: ((b*S + gq)*S + gk)  (< 2^26)
      const unsigned base = ((unsigned)bb * SEQ + (unsigned)(q0 + r)) * (unsigned)SEQ
                            + (unsigned)(k0 + part * 16);
      float sum = 0.0f;
#pragma unroll
      for (int j = 0; j < 16; ++j) {
        const float s = srow[j];
        float e = 0.0f;
        if (s > -1e29f) e = __expf(s - mn);
        sum += e;                          // denominator: no dropout
        const float u = tf_uniform(base + (unsigned)j);
        srow[j] = (u < 0.9f) ? e * ds : 0.0f;   // numerator: dropped+scaled
      }
      psum[r * 4 + part] = sum;
    }
    __syncthreads();

    if (t < TQ) {
      l_row[t] = l_row[t] * a_row[t] +
                 (psum[t * 4] + psum[t * 4 + 1] + psum[t * 4 + 2] + psum[t * 4 + 3]);
    }
    // rescale output accumulators by alpha
#pragma unroll
    for (int i = 0; i < 4; ++i) {
      const float al = a_row[r0 + i];
#pragma unroll
      for (int j = 0; j < 4; ++j) acc[i][j] *= al;
    }
    // ---- stage V (overwrite K buffer; K reads finished 3 barriers ago) ----
    {
      const float* vb = v + ((size_t)bb * SEQ + k0) * DIM;
      const int row0 = t >> 4;
      const int dd = (t & 15) * 4;
#pragma unroll
      for (int p = 0; p < 4; ++p) {
        const int rr = p * 16 + row0;
        const float4 val = *(const float4*)(vb + rr * DIM + dd);
        float* dst = &KVS[rr * PAD + dd];
        dst[0] = val.x; dst[1] = val.y; dst[2] = val.z; dst[3] = val.w;
      }
    }
    __syncthreads();

    // ---- O += P V ----
#pragma unroll 4
    for (int kk = 0; kk < TK; ++kk) {
      float pv[4], vv[4];
#pragma unroll
      for (int i = 0; i < 4; ++i) pv[i] = SS[(r0 + i) * PAD + kk];
#pragma unroll
      for (int j = 0; j < 4; ++j) vv[j] = KVS[kk * PAD + c0 + j];
#pragma unroll
      for (int i = 0; i < 4; ++i)
#pragma unroll
        for (int j = 0; j < 4; ++j)
          acc[i][j] = fmaf(pv[i], vv[j], acc[i][j]);
    }
    __syncthreads();   // protect SS/KVS for next tile
  }

  // ---- epilogue: divide by softmax denominator, store ----
  float* ob = out + ((size_t)bb * SEQ + q0) * DIM;
#pragma unroll
  for (int i = 0; i < 4; ++i) {
    const float inv = 1.0f / l_row[r0 + i];
    float4 o;
    o.x = acc[i][0] * inv; o.y = acc[i][1] * inv;
    o.z = acc[i][2] * inv; o.w = acc[i][3] * inv;
    *(float4*)(ob + (size_t)(r0 + i) * DIM + c0) = o;
  }
}

extern "C" void kernel_launch(void* const* d_in, const int* in_sizes, int n_in,
                              void* d_out, int out_size, void* d_ws, size_t ws_size,
                              hipStream_t stream) {
  const float* q = (const float*)d_in[0];
  const float* k = (const float*)d_in[1];
  const float* v = (const float*)d_in[2];
  const int* mask = (const int*)d_in[3];
  float* out = (float*)d_out;
  dim3 grid(BATCH * (SEQ / TQ));   // 512 blocks
  dim3 block(NTHREADS);
  hipLaunchKernelGGL(attn_fwd, grid, block, 0, stream, q, k, v, mask, out);
}

// Round 3
// 318.677 us; speedup vs baseline: 1.7354x; 1.7354x over previous
//
#include <hip/hip_runtime.h>

#define BATCH 16
#define SEQ   2048
#define DIM   64
#define TQ    64
#define TK    64
#define STR   72          // bf16 LDS row stride (16B-aligned rows, bank shift 4/row)
#define NTHREADS 256

typedef __attribute__((ext_vector_type(8))) short bf16x8;
typedef __attribute__((ext_vector_type(4))) float f32x4;

// ---- exact JAX *partitionable* threefry2x32, key = PRNGKey(42) -> (0, 42) ----
__device__ __forceinline__ unsigned rotl_(unsigned x, unsigned n) {
  return (x << n) | (x >> (32u - n));
}

__device__ __forceinline__ float tf_uniform(unsigned f) {
  unsigned x0 = 0u;        // counts_hi = 0 (total 2^26 < 2^32)
  unsigned x1 = f;         // counts_lo = f
  const unsigned ks0 = 0u;
  const unsigned ks1 = 42u;
  const unsigned ks2 = 0x1BD11BDAu ^ 42u;
  x0 += ks0; x1 += ks1;
#define TF_ROUND(r) { x0 += x1; x1 = rotl_(x1, r); x1 ^= x0; }
  TF_ROUND(13u) TF_ROUND(15u) TF_ROUND(26u) TF_ROUND(6u)
  x0 += ks1; x1 += ks2 + 1u;
  TF_ROUND(17u) TF_ROUND(29u) TF_ROUND(16u) TF_ROUND(24u)
  x0 += ks2; x1 += ks0 + 2u;
  TF_ROUND(13u) TF_ROUND(15u) TF_ROUND(26u) TF_ROUND(6u)
  x0 += ks0; x1 += ks1 + 3u;
  TF_ROUND(17u) TF_ROUND(29u) TF_ROUND(16u) TF_ROUND(24u)
  x0 += ks1; x1 += ks2 + 4u;
  TF_ROUND(13u) TF_ROUND(15u) TF_ROUND(26u) TF_ROUND(6u)
  x0 += ks2; x1 += ks0 + 5u;
#undef TF_ROUND
  const unsigned bits = x0 ^ x1;
  return __uint_as_float((bits >> 9) | 0x3F800000u) - 1.0f;   // [0,1)
}

// fp32 -> bf16, round-half-up (2 VALU ops; bias negligible vs bf16 eps)
__device__ __forceinline__ unsigned short to_bf16(float x) {
  return (unsigned short)((__float_as_uint(x) + 0x8000u) >> 16);
}

__global__ __launch_bounds__(NTHREADS, 2)
void attn_fwd(const float* __restrict__ q, const float* __restrict__ k,
              const float* __restrict__ v, const int* __restrict__ mask,
              float* __restrict__ out) {
  __shared__ unsigned short KS[TK * STR];    // K tile, [kcol][d] bf16
  __shared__ unsigned short VT[DIM * STR];   // V tile transposed, [d][krow] bf16
  __shared__ unsigned short PS[TQ * STR];    // P tile, [qrow][kcol] bf16 (wave-private bands)

  const int t    = threadIdx.x;
  const int w    = t >> 6;                  // wave 0..3 -> q rows 16w..16w+15
  const int lane = t & 63;
  const int tx   = lane & 15;               // MFMA m/n index
  const int quad = lane >> 4;               // 0..3
  const int bb   = blockIdx.x >> 5;         // batch
  const int q0   = (blockIdx.x & 31) * TQ;  // q-tile origin
  const float ds = (float)(1.0 / 0.9);

  // ---- preload Q A-fragments once (row = q0+16w+tx, k = 32*ks + quad*8 + j) ----
  bf16x8 aq[2];
  {
    const float* qr = q + ((size_t)bb * SEQ + q0 + 16 * w + tx) * DIM + quad * 8;
#pragma unroll
    for (int ks = 0; ks < 2; ++ks) {
      const float4 f0 = *(const float4*)(qr + ks * 32);
      const float4 f1 = *(const float4*)(qr + ks * 32 + 4);
      bf16x8 a;
      a[0] = (short)to_bf16(f0.x * 0.125f);
      a[1] = (short)to_bf16(f0.y * 0.125f);
      a[2] = (short)to_bf16(f0.z * 0.125f);
      a[3] = (short)to_bf16(f0.w * 0.125f);
      a[4] = (short)to_bf16(f1.x * 0.125f);
      a[5] = (short)to_bf16(f1.y * 0.125f);
      a[6] = (short)to_bf16(f1.z * 0.125f);
      a[7] = (short)to_bf16(f1.w * 0.125f);
      aq[ks] = a;
    }
  }

  float mrun[4], lrun[4];
  f32x4 oacc[4];
#pragma unroll
  for (int r = 0; r < 4; ++r) {
    mrun[r] = -1e30f; lrun[r] = 0.0f;
    oacc[r] = (f32x4){0.f, 0.f, 0.f, 0.f};
  }

  const int srow0 = t >> 4;          // staging row base 0..15
  const int sdd   = (t & 15) * 4;    // staging col base 0..60

#pragma unroll 1
  for (int kt = 0; kt < SEQ / TK; ++kt) {
    const int k0 = kt * TK;

    __syncthreads();   // protect KS/VT from previous tile's MFMA readers

    // ---- mask prefetch into registers (latency drains with staging vmcnt) ----
    int mv[4][4];
#pragma unroll
    for (int reg = 0; reg < 4; ++reg) {
      const size_t mrow = (size_t)(q0 + 16 * w + quad * 4 + reg) * SEQ + k0 + tx;
#pragma unroll
      for (int nt = 0; nt < 4; ++nt)
        mv[nt][reg] = mask[mrow + nt * 16];
    }

    // ---- stage K (row-major bf16) and V (transposed bf16) ----
    {
      const float* kb = k + ((size_t)bb * SEQ + k0) * DIM;
      const float* vb = v + ((size_t)bb * SEQ + k0) * DIM;
#pragma unroll
      for (int p = 0; p < 4; ++p) {
        const int rr = p * 16 + srow0;
        const float4 kv4 = *(const float4*)(kb + rr * DIM + sdd);
        ushort4 kk4;
        kk4.x = to_bf16(kv4.x); kk4.y = to_bf16(kv4.y);
        kk4.z = to_bf16(kv4.z); kk4.w = to_bf16(kv4.w);
        *(ushort4*)&KS[rr * STR + sdd] = kk4;
        const float4 vv4 = *(const float4*)(vb + rr * DIM + sdd);
        VT[(sdd + 0) * STR + rr] = to_bf16(vv4.x);
        VT[(sdd + 1) * STR + rr] = to_bf16(vv4.y);
        VT[(sdd + 2) * STR + rr] = to_bf16(vv4.z);
        VT[(sdd + 3) * STR + rr] = to_bf16(vv4.w);
      }
    }
    __syncthreads();

    // ---- S = Q K^T via MFMA: 4 col-tiles x 2 k-steps ----
    f32x4 qk[4];
#pragma unroll
    for (int nt = 0; nt < 4; ++nt) {
      f32x4 c = (f32x4){0.f, 0.f, 0.f, 0.f};
#pragma unroll
      for (int ks = 0; ks < 2; ++ks) {
        const bf16x8 b = *(const bf16x8*)&KS[(nt * 16 + tx) * STR + ks * 32 + quad * 8];
        c = __builtin_amdgcn_mfma_f32_16x16x32_bf16(aq[ks], b, c, 0, 0, 0);
      }
      qk[nt] = c;
    }

    // ---- online softmax in C-layout registers ----
    float al[4];
#pragma unroll
    for (int reg = 0; reg < 4; ++reg) {
      float mx = -1e30f;
#pragma unroll
      for (int nt = 0; nt < 4; ++nt)
        mx = fmaxf(mx, mv[nt][reg] ? qk[nt][reg] : -1e30f);
      mx = fmaxf(mx, __shfl_xor(mx, 1, 64));
      mx = fmaxf(mx, __shfl_xor(mx, 2, 64));
      mx = fmaxf(mx, __shfl_xor(mx, 4, 64));
      mx = fmaxf(mx, __shfl_xor(mx, 8, 64));
      const float mn = fmaxf(mrun[reg], mx);
      al[reg] = __expf(mrun[reg] - mn);
      mrun[reg] = mn;
    }

    // ---- exp + dropout (exact JAX threefry) + l partials; P -> LDS bf16 ----
#pragma unroll
    for (int reg = 0; reg < 4; ++reg) {
      const unsigned frow = (unsigned)(bb * SEQ + q0 + 16 * w + quad * 4 + reg) * (unsigned)SEQ
                            + (unsigned)(k0 + tx);
      const float mn = mrun[reg];
      float ls = 0.0f;
#pragma unroll
      for (int nt = 0; nt < 4; ++nt) {
        const float e = mv[nt][reg] ? __expf(qk[nt][reg] - mn) : 0.0f;
        ls += e;
        const float u = tf_uniform(frow + (unsigned)(nt * 16));
        const float p = (u < 0.9f) ? e * ds : 0.0f;
        PS[(16 * w + quad * 4 + reg) * STR + nt * 16 + tx] = to_bf16(p);
      }
      lrun[reg] = lrun[reg] * al[reg] + ls;
    }

    // ---- O = O*alpha + P V (wave-private PS band: no barrier needed) ----
#pragma unroll
    for (int nt = 0; nt < 4; ++nt) {
      f32x4 o = oacc[nt];
      o[0] *= al[0]; o[1] *= al[1]; o[2] *= al[2]; o[3] *= al[3];
      oacc[nt] = o;
    }
#pragma unroll
    for (int ks = 0; ks < 2; ++ks) {
      const bf16x8 ap = *(const bf16x8*)&PS[(16 * w + tx) * STR + ks * 32 + quad * 8];
#pragma unroll
      for (int nt = 0; nt < 4; ++nt) {
        const bf16x8 bv = *(const bf16x8*)&VT[(nt * 16 + tx) * STR + ks * 32 + quad * 8];
        oacc[nt] = __builtin_amdgcn_mfma_f32_16x16x32_bf16(ap, bv, oacc[nt], 0, 0, 0);
      }
    }
  }

  // ---- epilogue: reduce l across the 16-lane group, normalize, store ----
  float linv[4];
#pragma unroll
  for (int reg = 0; reg < 4; ++reg) {
    float ls = lrun[reg];
    ls += __shfl_xor(ls, 1, 64);
    ls += __shfl_xor(ls, 2, 64);
    ls += __shfl_xor(ls, 4, 64);
    ls += __shfl_xor(ls, 8, 64);
    linv[reg] = 1.0f / ls;
  }
  float* ob = out + ((size_t)bb * SEQ + q0 + 16 * w) * DIM;
#pragma unroll
  for (int nt = 0; nt < 4; ++nt)
#pragma unroll
    for (int reg = 0; reg < 4; ++reg)
      ob[(size_t)(quad * 4 + reg) * DIM + nt * 16 + tx] = oacc[nt][reg] * linv[reg];
}

extern "C" void kernel_launch(void* const* d_in, const int* in_sizes, int n_in,
                              void* d_out, int out_size, void* d_ws, size_t ws_size,
                              hipStream_t stream) {
  const float* q = (const float*)d_in[0];
  const float* k = (const float*)d_in[1];
  const float* v = (const float*)d_in[2];
  const int* mask = (const int*)d_in[3];
  float* out = (float*)d_out;
  dim3 grid(BATCH * (SEQ / TQ));   // 512 blocks = 2 blocks/CU
  dim3 block(NTHREADS);
  hipLaunchKernelGGL(attn_fwd, grid, block, 0, stream, q, k, v, mask, out);
}